// Round 1
// baseline (131.113 us; speedup 1.0000x reference)
//
#include <hip/hip_runtime.h>
#include <hip/hip_bf16.h>

// Problem constants (N,C,K,H,W) = (4,3,21,128,128), SCALE=0.5 -> Ho=Wo=64, P=4096
// loss = -(WEIGHT/N) * sum_{n,p,q} gate[p] * exp(-0.5*||f_p-f_q||^2) * sum_k S[k,p]S[k,q]
//   f = [x/50, y/50, r/15, g/15, b/15],  S = bilinear(seg)*roi,
//   gate = max( unlabeled ? 1 : roi - max_k bilinear(seg), 0 )

#define NIMG 4
#define KCH 21
#define HIN 128
#define WIN 128
#define HO 64
#define WO 64
#define PPX 4096            // HO*WO
#define ROWF 32             // floats per row in workspace: [0..20]=S, [21..23]=0,
                            // [24]=fx [25]=fy [26]=r [27]=g [28]=b [29]=sq [30]=gate [31]=0

__global__ __launch_bounds__(256) void prep_kernel(
    const float* __restrict__ img, const float* __restrict__ seg,
    const float* __restrict__ roi, const int* __restrict__ lbl,
    float* __restrict__ ws)
{
    int gid = blockIdx.x * 256 + threadIdx.x;       // 0 .. NIMG*PPX-1
    int n = gid >> 12;
    int p = gid & (PPX - 1);
    int y = p >> 6, x = p & 63;
    int iy = 2 * y, ix = 2 * x;

    const float inv_rgb = 1.0f / 15.0f;             // SIGMA_RGB
    const float inv_sxy = 1.0f / 50.0f;             // SIGMA_XY * SCALE

    float r = img[(((size_t)n * 3 + 0) * HIN + iy) * WIN + ix] * inv_rgb;
    float g = img[(((size_t)n * 3 + 1) * HIN + iy) * WIN + ix] * inv_rgb;
    float b = img[(((size_t)n * 3 + 2) * HIN + iy) * WIN + ix] * inv_rgb;
    float fx = (float)x * inv_sxy;
    float fy = (float)y * inv_sxy;
    float sq = fx * fx + fy * fy + r * r + g * g + b * b;

    float rv = roi[((size_t)n * HIN + iy) * WIN + ix];
    int   lb = lbl[((size_t)n * HIN + iy) * WIN + ix];

    float* row = ws + ((size_t)n * PPX + p) * ROWF;

    float m = -1e30f;
    #pragma unroll
    for (int k = 0; k < KCH; k++) {
        const float* sp = seg + ((((size_t)n * KCH + k) * HIN + iy) * WIN + ix);
        float2 a = *(const float2*)sp;
        float2 c = *(const float2*)(sp + WIN);
        float s = 0.25f * (a.x + a.y + c.x + c.y);   // bilinear, scale=2 exact
        m = fmaxf(m, s);
        row[k] = s * rv;                             // seg_roi
    }
    row[21] = 0.0f; row[22] = 0.0f; row[23] = 0.0f;

    float gate = (lb == 255) ? 1.0f : (rv - m);
    gate = fmaxf(gate, 0.0f);

    row[24] = fx; row[25] = fy; row[26] = r; row[27] = g; row[28] = b;
    row[29] = sq; row[30] = gate; row[31] = 0.0f;
}

#define QTILE 512
#define PTILE 128
#define NQT (PPX / QTILE)    // 8
#define NPT (PPX / PTILE)    // 32

__global__ __launch_bounds__(256) void pairs_kernel(
    const float* __restrict__ ws, float* __restrict__ out)
{
    __shared__ float4 lds[PTILE * 8];    // 128 rows * 32 floats = 16 KB
    __shared__ float wavesum[4];

    int blk = blockIdx.x;
    int n   = blk / (NQT * NPT);
    int rem = blk - n * (NQT * NPT);
    int qt  = rem / NPT;
    int pt  = rem - qt * NPT;

    const float* base = ws + (size_t)n * PPX * ROWF;
    int t = threadIdx.x;

    // Stage PTILE p-rows into LDS (flat contiguous copy, coalesced)
    const float4* src = (const float4*)(base + (size_t)pt * PTILE * ROWF);
    #pragma unroll
    for (int i = 0; i < 4; i++) lds[i * 256 + t] = src[i * 256 + t];

    // Load 2 q-rows into registers
    float4 Sq[2][6], Fa[2], Fb[2];
    #pragma unroll
    for (int j = 0; j < 2; j++) {
        const float4* qr = (const float4*)(base + (size_t)(qt * QTILE + j * 256 + t) * ROWF);
        #pragma unroll
        for (int u = 0; u < 6; u++) Sq[j][u] = qr[u];
        Fa[j] = qr[6];
        Fb[j] = qr[7];
    }
    __syncthreads();

    float acc = 0.0f;
    for (int ip = 0; ip < PTILE; ip++) {
        const float4* row = &lds[ip * 8];
        float4 s0 = row[0], s1 = row[1], s2 = row[2];
        float4 s3 = row[3], s4 = row[4], s5 = row[5];
        float4 fa = row[6], fb = row[7];
        float sqp = fb.y, gp = fb.z;

        #pragma unroll
        for (int j = 0; j < 2; j++) {
            // 5-dim feature dot
            float dot5;
            dot5 = fa.x * Fa[j].x;
            dot5 = fmaf(fa.y, Fa[j].y, dot5);
            dot5 = fmaf(fa.z, Fa[j].z, dot5);
            dot5 = fmaf(fa.w, Fa[j].w, dot5);
            dot5 = fmaf(fb.x, Fb[j].x, dot5);
            float d2 = fmaxf(sqp + Fb[j].y - 2.0f * dot5, 0.0f);
            float w = __expf(-0.5f * d2);

            // K-dot over 24 (pads are zero)
            float dK;
            dK = s0.x * Sq[j][0].x;
            dK = fmaf(s0.y, Sq[j][0].y, dK);
            dK = fmaf(s0.z, Sq[j][0].z, dK);
            dK = fmaf(s0.w, Sq[j][0].w, dK);
            dK = fmaf(s1.x, Sq[j][1].x, dK);
            dK = fmaf(s1.y, Sq[j][1].y, dK);
            dK = fmaf(s1.z, Sq[j][1].z, dK);
            dK = fmaf(s1.w, Sq[j][1].w, dK);
            dK = fmaf(s2.x, Sq[j][2].x, dK);
            dK = fmaf(s2.y, Sq[j][2].y, dK);
            dK = fmaf(s2.z, Sq[j][2].z, dK);
            dK = fmaf(s2.w, Sq[j][2].w, dK);
            dK = fmaf(s3.x, Sq[j][3].x, dK);
            dK = fmaf(s3.y, Sq[j][3].y, dK);
            dK = fmaf(s3.z, Sq[j][3].z, dK);
            dK = fmaf(s3.w, Sq[j][3].w, dK);
            dK = fmaf(s4.x, Sq[j][4].x, dK);
            dK = fmaf(s4.y, Sq[j][4].y, dK);
            dK = fmaf(s4.z, Sq[j][4].z, dK);
            dK = fmaf(s4.w, Sq[j][4].w, dK);
            dK = fmaf(s5.x, Sq[j][5].x, dK);
            dK = fmaf(s5.y, Sq[j][5].y, dK);
            dK = fmaf(s5.z, Sq[j][5].z, dK);
            dK = fmaf(s5.w, Sq[j][5].w, dK);

            acc = fmaf(w * gp, dK, acc);
        }
    }

    // Reduce: wave (64) shuffle, then across the 4 waves via LDS
    #pragma unroll
    for (int off = 32; off > 0; off >>= 1)
        acc += __shfl_down(acc, off, 64);
    if ((t & 63) == 0) wavesum[t >> 6] = acc;
    __syncthreads();
    if (t == 0) {
        float s = wavesum[0] + wavesum[1] + wavesum[2] + wavesum[3];
        // loss = -(WEIGHT/N) * total
        atomicAdd(out, s * (-1e-7f / (float)NIMG));
    }
}

extern "C" void kernel_launch(void* const* d_in, const int* in_sizes, int n_in,
                              void* d_out, int out_size, void* d_ws, size_t ws_size,
                              hipStream_t stream) {
    const float* images = (const float*)d_in[0];   // [4,3,128,128]
    const float* seg    = (const float*)d_in[1];   // [4,21,128,128]
    const float* rois   = (const float*)d_in[2];   // [4,128,128]
    const int*   lbl    = (const int*)d_in[3];     // [4,1,128,128]
    float* out = (float*)d_out;
    float* ws  = (float*)d_ws;                     // needs 4*4096*32*4 = 2 MB

    hipMemsetAsync(out, 0, sizeof(float), stream);

    hipLaunchKernelGGL(prep_kernel, dim3((NIMG * PPX) / 256), dim3(256), 0, stream,
                       images, seg, rois, lbl, ws);
    hipLaunchKernelGGL(pairs_kernel, dim3(NIMG * NQT * NPT), dim3(256), 0, stream,
                       ws, out);
}

// Round 2
// 123.001 us; speedup vs baseline: 1.0660x; 1.0660x over previous
//
#include <hip/hip_runtime.h>
#include <hip/hip_bf16.h>

// (N,C,K,H,W) = (4,3,21,128,128), SCALE=0.5 -> Ho=Wo=64, P=4096
// loss = -(WEIGHT/N) * sum_{n,p,q} gate[p] * exp(-0.5*||f_p-f_q||^2) * sum_k S[k,p]S[k,q]
//   f = [x/50, y/50, r/15, g/15, b/15],  S = bilinear(seg)*roi  (f16 — S in [0,1]),
//   gate = unlabeled ? 1 : max(roi - max_k bilinear(seg), 0)   (exploits roi in {0,1})
//
// ws layout: [0, 688128)           : Splane f16 [n][k][4096]  (raw bilinear seg, pre-roi)
//            [0xB0000, +1572864)   : rows  [n][4096] x 96B:
//              dw0..11  = 24 f16:  S[0..20], 0,0,0
//              dw12..18 = fx fy r g b sq gate   dw19..23 = 0

#define NIMG 4
#define KCH 21
#define HIN 128
#define WIN 128
#define PPX 4096
#define ROWDW 24            // 96 B per pixel row
#define QPT 4               // q-rows per thread
#define QTILE 1024          // 256 threads * QPT
#define NQT 4               // PPX / QTILE
#define PTILE 128
#define NPT 32              // PPX / PTILE
#define ROWS_OFF 0xB0000

typedef _Float16 h2 __attribute__((ext_vector_type(2)));
typedef _Float16 h4 __attribute__((ext_vector_type(4)));

union F4 { float4 v; float f[4]; h2 h[4]; };

#if __has_builtin(__builtin_amdgcn_fdot2)
__device__ __forceinline__ float fdot2f(h2 a, h2 b, float c) {
    return __builtin_amdgcn_fdot2(a, b, c, false);
}
#else
__device__ __forceinline__ float fdot2f(h2 a, h2 b, float c) {
    return fmaf((float)a.x, (float)b.x, fmaf((float)a.y, (float)b.y, c));
}
#endif

// ---- prep_s: bilinear-downsample seg (scale=2 exact: avg of 2x2) -> f16 plane ----
// one thread per (n,k,y,x4): 4 consecutive output x
__global__ __launch_bounds__(256) void prep_s(
    const float* __restrict__ seg, _Float16* __restrict__ Splane)
{
    int gid = blockIdx.x * 256 + threadIdx.x;   // 4*21*64*16 = 86016
    int x4 = gid & 15;
    int y  = (gid >> 4) & 63;
    int nk = gid >> 10;                         // n*21+k, 0..83

    const float* s0 = seg + ((size_t)nk * HIN + 2 * y) * WIN + 8 * x4;
    float4 a0 = *(const float4*)s0;
    float4 a1 = *(const float4*)(s0 + 4);
    float4 b0 = *(const float4*)(s0 + WIN);
    float4 b1 = *(const float4*)(s0 + WIN + 4);

    h4 o;
    o.x = (_Float16)(0.25f * (a0.x + a0.y + b0.x + b0.y));
    o.y = (_Float16)(0.25f * (a0.z + a0.w + b0.z + b0.w));
    o.z = (_Float16)(0.25f * (a1.x + a1.y + b1.x + b1.y));
    o.w = (_Float16)(0.25f * (a1.z + a1.w + b1.z + b1.w));
    *(h4*)(Splane + (size_t)nk * PPX + y * 64 + 4 * x4) = o;
}

// ---- prep_b: per-pixel row assembly (S*roi packed f16, features, gate) ----
__global__ __launch_bounds__(64) void prep_b(
    const float* __restrict__ img, const float* __restrict__ roi,
    const int* __restrict__ lbl, const _Float16* __restrict__ Splane,
    float* __restrict__ rows, float* __restrict__ out)
{
    int gid = blockIdx.x * 64 + threadIdx.x;    // 16384
    if (gid == 0) out[0] = 0.0f;
    int n = gid >> 12;
    int p = gid & (PPX - 1);
    int y = p >> 6, x = p & 63;
    int iy = 2 * y, ix = 2 * x;

    const float inv_rgb = 1.0f / 15.0f;
    const float inv_sxy = 1.0f / 50.0f;

    float r = img[(((size_t)n * 3 + 0) * HIN + iy) * WIN + ix] * inv_rgb;
    float g = img[(((size_t)n * 3 + 1) * HIN + iy) * WIN + ix] * inv_rgb;
    float b = img[(((size_t)n * 3 + 2) * HIN + iy) * WIN + ix] * inv_rgb;
    float fx = (float)x * inv_sxy;
    float fy = (float)y * inv_sxy;
    float sq = fx * fx + fy * fy + r * r + g * g + b * b;

    float rv = roi[((size_t)n * HIN + iy) * WIN + ix];
    int   lb = lbl[((size_t)n * HIN + iy) * WIN + ix];

    union { float f[ROWDW]; _Float16 h[2 * ROWDW]; } row;
    float maxs = 0.0f;
    #pragma unroll
    for (int k = 0; k < KCH; k++) {
        float s = (float)Splane[((size_t)n * KCH + k) * PPX + p];
        maxs = fmaxf(maxs, s);
        row.h[k] = (_Float16)(s * rv);
    }
    row.h[21] = (_Float16)0.f; row.h[22] = (_Float16)0.f; row.h[23] = (_Float16)0.f;

    float gate = (lb == 255) ? 1.0f : fmaxf(rv - maxs, 0.0f);

    row.f[12] = fx; row.f[13] = fy; row.f[14] = r; row.f[15] = g;
    row.f[16] = b;  row.f[17] = sq; row.f[18] = gate; row.f[19] = 0.0f;
    row.f[20] = 0.0f; row.f[21] = 0.0f; row.f[22] = 0.0f; row.f[23] = 0.0f;

    float4* dst = (float4*)(rows + (size_t)gid * ROWDW);
    const float4* srcv = (const float4*)row.f;
    #pragma unroll
    for (int i = 0; i < 6; i++) dst[i] = srcv[i];
}

// ---- pairs: per block, QTILE q-rows (4/thread, register-resident) x PTILE p-rows (LDS) ----
__global__ __launch_bounds__(256, 2) void pairs_kernel(
    const float* __restrict__ rows, float* __restrict__ out)
{
    __shared__ float4 tile[PTILE * 6];   // 12 KB
    __shared__ float wavesum[4];

    int blk = blockIdx.x;                // n(4) x qt(4) x pt(32) = 512
    int pt = blk & 31;
    int qt = (blk >> 5) & 3;
    int n  = blk >> 7;

    const float* base = rows + (size_t)n * PPX * ROWDW;
    int t = threadIdx.x;

    // stage p-tile: 128 rows * 96B = 768 float4, coalesced
    const float4* src = (const float4*)(base + (size_t)pt * PTILE * ROWDW);
    tile[t] = src[t];
    tile[t + 256] = src[t + 256];
    tile[t + 512] = src[t + 512];

    // q-rows -> registers
    h2    qS[QPT][12];
    float qfx[QPT], qfy[QPT], qr[QPT], qg[QPT], qb[QPT], qsq[QPT];
    #pragma unroll
    for (int j = 0; j < QPT; j++) {
        const float4* qp = (const float4*)(base + (size_t)(qt * QTILE + j * 256 + t) * ROWDW);
        F4 u0, u1, u2, u3, u4;
        u0.v = qp[0]; u1.v = qp[1]; u2.v = qp[2]; u3.v = qp[3]; u4.v = qp[4];
        #pragma unroll
        for (int i = 0; i < 4; i++) { qS[j][i] = u0.h[i]; qS[j][4 + i] = u1.h[i]; qS[j][8 + i] = u2.h[i]; }
        qfx[j] = u3.f[0]; qfy[j] = u3.f[1]; qr[j] = u3.f[2]; qg[j] = u3.f[3];
        qb[j] = u4.f[0]; qsq[j] = u4.f[1];
    }
    __syncthreads();

    float acc = 0.0f;
    for (int ip = 0; ip < PTILE; ip++) {
        const float4* rp = &tile[ip * 6];
        F4 p0, p1, p2, p3, p4;
        p0.v = rp[0]; p1.v = rp[1]; p2.v = rp[2]; p3.v = rp[3]; p4.v = rp[4];
        float pfx = p3.f[0], pfy = p3.f[1], pr = p3.f[2], pg = p3.f[3];
        float pb = p4.f[0], psq = p4.f[1], pgate = p4.f[2];

        float tsum = 0.0f;
        #pragma unroll
        for (int j = 0; j < QPT; j++) {
            float dot5;
            dot5 = pfx * qfx[j];
            dot5 = fmaf(pfy, qfy[j], dot5);
            dot5 = fmaf(pr,  qr[j],  dot5);
            dot5 = fmaf(pg,  qg[j],  dot5);
            dot5 = fmaf(pb,  qb[j],  dot5);
            float d2 = fmaxf(fmaf(-2.0f, dot5, psq + qsq[j]), 0.0f);
            float w = __expf(-0.5f * d2);

            float dK = 0.0f;
            dK = fdot2f(p0.h[0], qS[j][0], dK);
            dK = fdot2f(p0.h[1], qS[j][1], dK);
            dK = fdot2f(p0.h[2], qS[j][2], dK);
            dK = fdot2f(p0.h[3], qS[j][3], dK);
            dK = fdot2f(p1.h[0], qS[j][4], dK);
            dK = fdot2f(p1.h[1], qS[j][5], dK);
            dK = fdot2f(p1.h[2], qS[j][6], dK);
            dK = fdot2f(p1.h[3], qS[j][7], dK);
            dK = fdot2f(p2.h[0], qS[j][8], dK);
            dK = fdot2f(p2.h[1], qS[j][9], dK);
            dK = fdot2f(p2.h[2], qS[j][10], dK);
            dK = fdot2f(p2.h[3], qS[j][11], dK);

            tsum = fmaf(w, dK, tsum);
        }
        acc = fmaf(pgate, tsum, acc);
    }

    #pragma unroll
    for (int off = 32; off > 0; off >>= 1)
        acc += __shfl_down(acc, off, 64);
    if ((t & 63) == 0) wavesum[t >> 6] = acc;
    __syncthreads();
    if (t == 0) {
        float s = wavesum[0] + wavesum[1] + wavesum[2] + wavesum[3];
        atomicAdd(out, s * (-1e-7f / (float)NIMG));
    }
}

extern "C" void kernel_launch(void* const* d_in, const int* in_sizes, int n_in,
                              void* d_out, int out_size, void* d_ws, size_t ws_size,
                              hipStream_t stream) {
    const float* images = (const float*)d_in[0];   // [4,3,128,128]
    const float* seg    = (const float*)d_in[1];   // [4,21,128,128]
    const float* rois   = (const float*)d_in[2];   // [4,128,128]
    const int*   lbl    = (const int*)d_in[3];     // [4,1,128,128]
    float* out = (float*)d_out;

    _Float16* Splane = (_Float16*)d_ws;
    float*    rows   = (float*)((char*)d_ws + ROWS_OFF);

    hipLaunchKernelGGL(prep_s, dim3((NIMG * KCH * 64 * 16) / 256), dim3(256), 0, stream,
                       seg, Splane);
    hipLaunchKernelGGL(prep_b, dim3((NIMG * PPX) / 64), dim3(64), 0, stream,
                       images, rois, lbl, Splane, rows, out);
    hipLaunchKernelGGL(pairs_kernel, dim3(NIMG * NQT * NPT), dim3(256), 0, stream,
                       rows, out);
}

// Round 4
// 90.739 us; speedup vs baseline: 1.4450x; 1.3555x over previous
//
#include <hip/hip_runtime.h>
#include <hip/hip_bf16.h>

// (N,C,K,H,W) = (4,3,21,128,128), SCALE=0.5 -> Ho=Wo=64, P=4096
// loss = -(WEIGHT/N) * sum_{n,p,q} gate_p * exp(-0.5*d2(p,q)) * sum_k S_kp S_kq
// MFMA: c1 = (gate_p*S_p)·S_q  via 2x mfma_32x32x16_f16 (K=21 pad 32, f16)
//       c2 = f_p·f_q exact via hi/lo split: A=[hi,lo], B1=[hi,hi], B2=[lo,lo]
//            c2 = A·B1 + A·B2 = (hi+lo)_p·(hi+lo)_q   (f16 products exact in fp32)
//   arg = c*(sq_p+sq_q) + (-2c)*c2, c = -0.5*log2(e);  w = exp2(min(arg,0)); acc += w*c1
// Reduction: per-block partial -> ws, deterministic fixed-tree finalize -> out[0].

typedef _Float16 v8h __attribute__((ext_vector_type(8)));
typedef float v16f __attribute__((ext_vector_type(16)));

#define NIMG 4
#define KCH 21
#define HIN 128
#define WIN 128
#define PPX 4096

// ws layout
#define SG_OFF   0x000000   // gated S f16, 48B/pixel
#define SR_OFF   0x0C0000   // raw   S f16, 48B/pixel
#define FT_OFF   0x180000   // features [hi(5),0,0,0 | lo(5),0,0,0] f16, 32B/pixel
#define SQ_OFF   0x200000   // c*|f|^2 f32, 4B/pixel
#define PART_OFF 0x210000   // 1024 block partials f32

#define CEXP -0.72134752044448170f   // -0.5*log2(e)
#define M2C   1.44269504088896341f   // -2*CEXP

__device__ __forceinline__ float fexp2(float x) {
#if __has_builtin(__builtin_amdgcn_exp2f)
    return __builtin_amdgcn_exp2f(x);
#else
    return __expf(x * 0.69314718055994531f);
#endif
}

// ---- prep ----
__global__ __launch_bounds__(256) void prep_kernel(
    const float* __restrict__ img, const float* __restrict__ seg,
    const float* __restrict__ roi, const int* __restrict__ lbl,
    char* __restrict__ ws)
{
    int gid = blockIdx.x * 256 + threadIdx.x;     // 16384
    int n = gid >> 12, p = gid & (PPX - 1);
    int y = p >> 6, x = p & 63, iy = 2 * y, ix = 2 * x;
    const float inv_rgb = 1.0f / 15.0f, inv_sxy = 1.0f / 50.0f;

    float rv = roi[((size_t)n * HIN + iy) * WIN + ix];
    int   lb = lbl[((size_t)n * HIN + iy) * WIN + ix];

    float sv[KCH]; float maxs = 0.0f;
    #pragma unroll
    for (int k = 0; k < KCH; k++) {
        const float* sp = seg + ((((size_t)n * KCH + k) * HIN + iy) * WIN + ix);
        float2 a = *(const float2*)sp;
        float2 c = *(const float2*)(sp + WIN);
        float s = 0.25f * (a.x + a.y + c.x + c.y);
        maxs = fmaxf(maxs, s);
        sv[k] = s * rv;
    }
    float gate = (lb == 255) ? 1.0f : fmaxf(rv - maxs, 0.0f);

    union { v8h h[3]; _Float16 e[24]; } rr, gg;
    #pragma unroll
    for (int k = 0; k < KCH; k++) {
        rr.e[k] = (_Float16)sv[k];
        gg.e[k] = (_Float16)(sv[k] * gate);
    }
    #pragma unroll
    for (int k = KCH; k < 24; k++) { rr.e[k] = (_Float16)0.f; gg.e[k] = (_Float16)0.f; }

    v8h* sgp = (v8h*)(ws + SG_OFF + (size_t)gid * 48);
    v8h* srp = (v8h*)(ws + SR_OFF + (size_t)gid * 48);
    sgp[0] = gg.h[0]; sgp[1] = gg.h[1]; sgp[2] = gg.h[2];
    srp[0] = rr.h[0]; srp[1] = rr.h[1]; srp[2] = rr.h[2];

    float f[5];
    f[0] = (float)x * inv_sxy;
    f[1] = (float)y * inv_sxy;
    f[2] = img[(((size_t)n * 3 + 0) * HIN + iy) * WIN + ix] * inv_rgb;
    f[3] = img[(((size_t)n * 3 + 1) * HIN + iy) * WIN + ix] * inv_rgb;
    f[4] = img[(((size_t)n * 3 + 2) * HIN + iy) * WIN + ix] * inv_rgb;

    union { v8h h[2]; _Float16 e[16]; } ff;
    float sq = 0.f;
    #pragma unroll
    for (int i = 0; i < 5; i++) {
        _Float16 hi = (_Float16)f[i];
        _Float16 lo = (_Float16)(f[i] - (float)hi);
        ff.e[i] = hi; ff.e[8 + i] = lo;
        float fe = (float)hi + (float)lo;
        sq = fmaf(fe, fe, sq);
    }
    #pragma unroll
    for (int i = 5; i < 8; i++) { ff.e[i] = (_Float16)0.f; ff.e[8 + i] = (_Float16)0.f; }

    v8h* ftp = (v8h*)(ws + FT_OFF + (size_t)gid * 32);
    ftp[0] = ff.h[0]; ftp[1] = ff.h[1];
    *(float*)(ws + SQ_OFF + (size_t)gid * 4) = CEXP * sq;
}

// ---- pairs: block = 512 p x 128 q; waves 2x2 over 64x64; 32x32 MFMA subtiles ----
// LDS: S rows stride 72 (48B data + 16B zero-pad + 8), F rows stride 40 (32B data + 8)
#define QS_O 0
#define QF_O 9216
#define QQ_O 14336
#define PS_O 14848
#define PF_O 24064
#define PQ_O 29184
#define RED_O 29696
#define LDS_BYTES 29712

__global__ __launch_bounds__(256) void pairs_kernel(
    const char* __restrict__ ws, float* __restrict__ part)
{
    __shared__ __align__(16) char smem[LDS_BYTES];
    int b = blockIdx.x;                 // 1024 = ps(8) x qt(32) x n(4)
    int ps = b & 7, qt = (b >> 3) & 31, n = b >> 8;
    int t = threadIdx.x;
    int lane = t & 63, half = lane >> 5, lr = lane & 31, wv = t >> 6;
    int wq = wv & 1, wp = wv >> 1;

    const float* SGg = (const float*)(ws + SG_OFF);   // 12 dw / row
    const float* SRg = (const float*)(ws + SR_OFF);
    const float* FTg = (const float*)(ws + FT_OFF);   // 8 dw / row
    const float* SQg = (const float*)(ws + SQ_OFF);

    // zero the S K-pad regions (bytes 48..63 of each row)
    if (t < 128) {
        *(float2*)(smem + QS_O + t * 72 + 48) = make_float2(0.f, 0.f);
        *(float2*)(smem + QS_O + t * 72 + 56) = make_float2(0.f, 0.f);
        *(float2*)(smem + PS_O + t * 72 + 48) = make_float2(0.f, 0.f);
        *(float2*)(smem + PS_O + t * 72 + 56) = make_float2(0.f, 0.f);
    }

    // ---- stage q-side (block-constant): raw S + features + sq ----
    {
        int qbase = n * PPX + qt * 128;
        const float* gS = SRg + (size_t)qbase * 12;
        #pragma unroll
        for (int i = 0; i < 6; i++) {
            int d = t + i * 256;
            int row = d / 12, off = d - row * 12;
            *(float*)(smem + QS_O + row * 72 + off * 4) = gS[d];
        }
        const float* gF = FTg + (size_t)qbase * 8;
        #pragma unroll
        for (int i = 0; i < 4; i++) {
            int d = t + i * 256;
            int row = d >> 3, off = d & 7;
            *(float*)(smem + QF_O + row * 40 + off * 4) = gF[d];
        }
        if (t < 128) *(float*)(smem + QQ_O + t * 4) = SQg[qbase + t];
    }
    __syncthreads();

    // ---- B fragments (block-resident) ----
    v8h BS[2][2], BFH[2], BFL[2]; float sqq[2];
    #pragma unroll
    for (int s = 0; s < 2; s++) {
        int cr = wq * 64 + s * 32 + lr;
        const char* rb = smem + QS_O + cr * 72 + half * 16;
        union { v8h h; float2 f[2]; } u0, u1, uh, ul;
        u0.f[0] = *(const float2*)(rb);        u0.f[1] = *(const float2*)(rb + 8);
        u1.f[0] = *(const float2*)(rb + 32);   u1.f[1] = *(const float2*)(rb + 40);
        const char* fb = smem + QF_O + cr * 40;
        uh.f[0] = *(const float2*)(fb);        uh.f[1] = *(const float2*)(fb + 8);
        ul.f[0] = *(const float2*)(fb + 16);   ul.f[1] = *(const float2*)(fb + 24);
        BS[s][0] = u0.h; BS[s][1] = u1.h; BFH[s] = uh.h; BFL[s] = ul.h;
        sqq[s] = *(const float*)(smem + QQ_O + cr * 4);
    }

    float a0c = 0.f, a1c = 0.f, a2c = 0.f, a3c = 0.f;
    int pbase0 = n * PPX + ps * 512;

    for (int ch = 0; ch < 4; ch++) {
        __syncthreads();                      // prior reads of PS/PF done before overwrite
        int pbase = pbase0 + ch * 128;
        const float* gS = SGg + (size_t)pbase * 12;
        #pragma unroll
        for (int i = 0; i < 6; i++) {
            int d = t + i * 256;
            int row = d / 12, off = d - row * 12;
            *(float*)(smem + PS_O + row * 72 + off * 4) = gS[d];
        }
        const float* gF = FTg + (size_t)pbase * 8;
        #pragma unroll
        for (int i = 0; i < 4; i++) {
            int d = t + i * 256;
            int row = d >> 3, off = d & 7;
            *(float*)(smem + PF_O + row * 40 + off * 4) = gF[d];
        }
        if (t < 128) *(float*)(smem + PQ_O + t * 4) = SQg[pbase + t];
        __syncthreads();

        #pragma unroll
        for (int sp = 0; sp < 2; sp++) {
            int pr = wp * 64 + sp * 32 + lr;
            union { v8h h; float2 f[2]; } a0, a1, af;
            const char* rb = smem + PS_O + pr * 72 + half * 16;
            a0.f[0] = *(const float2*)(rb);        a0.f[1] = *(const float2*)(rb + 8);
            a1.f[0] = *(const float2*)(rb + 32);   a1.f[1] = *(const float2*)(rb + 40);
            const char* fb2 = smem + PF_O + pr * 40 + half * 16;   // [hi,lo] A-pack
            af.f[0] = *(const float2*)(fb2);       af.f[1] = *(const float2*)(fb2 + 8);

            float sqp[16];
            int pr0 = wp * 64 + sp * 32 + half * 4;
            #pragma unroll
            for (int r = 0; r < 16; r++) {
                int row = pr0 + (r & 3) + 8 * (r >> 2);   // C-layout row
                sqp[r] = *(const float*)(smem + PQ_O + row * 4);
            }

            #pragma unroll
            for (int s = 0; s < 2; s++) {
                v16f z = {0.f,0.f,0.f,0.f,0.f,0.f,0.f,0.f,0.f,0.f,0.f,0.f,0.f,0.f,0.f,0.f};
                v16f c2 = __builtin_amdgcn_mfma_f32_32x32x16_f16(af.h, BFH[s], z, 0, 0, 0);
                c2 = __builtin_amdgcn_mfma_f32_32x32x16_f16(af.h, BFL[s], c2, 0, 0, 0);
                v16f c1 = __builtin_amdgcn_mfma_f32_32x32x16_f16(a0.h, BS[s][0], z, 0, 0, 0);
                c1 = __builtin_amdgcn_mfma_f32_32x32x16_f16(a1.h, BS[s][1], c1, 0, 0, 0);
                float sqv = sqq[s];
                #pragma unroll
                for (int r = 0; r < 16; r++) {
                    float arg = fmaf(M2C, c2[r], sqp[r] + sqv);
                    arg = fminf(arg, 0.0f);
                    float w = fexp2(arg);
                    float v = w * c1[r];
                    if ((r & 3) == 0) a0c += v;
                    else if ((r & 3) == 1) a1c += v;
                    else if ((r & 3) == 2) a2c += v;
                    else a3c += v;
                }
            }
        }
    }

    float acc = (a0c + a1c) + (a2c + a3c);
    #pragma unroll
    for (int off = 32; off > 0; off >>= 1) acc += __shfl_down(acc, off, 64);
    float* wred = (float*)(smem + RED_O);
    if ((t & 63) == 0) wred[t >> 6] = acc;
    __syncthreads();
    if (t == 0)
        part[blockIdx.x] = (wred[0] + wred[1]) + (wred[2] + wred[3]);
}

// ---- finalize: deterministic fixed-tree sum of 1024 partials ----
__global__ __launch_bounds__(256) void finalize_kernel(
    const float* __restrict__ part, float* __restrict__ out)
{
    __shared__ float s[256];
    int t = threadIdx.x;
    float v = ((part[t] + part[t + 256]) + (part[t + 512] + part[t + 768]));
    s[t] = v;
    __syncthreads();
    #pragma unroll
    for (int off = 128; off > 0; off >>= 1) {
        if (t < off) s[t] += s[t + off];
        __syncthreads();
    }
    if (t == 0) out[0] = s[0] * (-1e-7f / (float)NIMG);
}

extern "C" void kernel_launch(void* const* d_in, const int* in_sizes, int n_in,
                              void* d_out, int out_size, void* d_ws, size_t ws_size,
                              hipStream_t stream) {
    const float* images = (const float*)d_in[0];   // [4,3,128,128]
    const float* seg    = (const float*)d_in[1];   // [4,21,128,128]
    const float* rois   = (const float*)d_in[2];   // [4,128,128]
    const int*   lbl    = (const int*)d_in[3];     // [4,1,128,128]
    float* out = (float*)d_out;
    char*  ws  = (char*)d_ws;
    float* part = (float*)(ws + PART_OFF);

    hipLaunchKernelGGL(prep_kernel, dim3((NIMG * PPX) / 256), dim3(256), 0, stream,
                       images, seg, rois, lbl, ws);
    hipLaunchKernelGGL(pairs_kernel, dim3(NIMG * 32 * 8), dim3(256), 0, stream,
                       (const char*)ws, part);
    hipLaunchKernelGGL(finalize_kernel, dim3(1), dim3(256), 0, stream,
                       (const float*)part, out);
}